// Round 1
// baseline (14068.797 us; speedup 1.0000x reference)
//
#include <hip/hip_runtime.h>
#include <stdint.h>

// ============================================================================
// Decoder_24799141167169: 8-step LSTM warp + 5-layer weight-normed SDF decoder
// Strategy: single persistent fused kernel (row-local recurrence), bf16 MFMA
// 16x16x32, weights pre-packed fragment-major by a prep kernel into d_ws.
// ============================================================================

typedef short v8s __attribute__((ext_vector_type(8)));
typedef float v4f __attribute__((ext_vector_type(4)));

#define MFMA16(a, b, c) __builtin_amdgcn_mfma_f32_16x16x32_bf16((a), (b), (c), 0, 0, 0)

static __device__ __forceinline__ unsigned short f2bf(float f) {
  union { float f; uint32_t u; } x; x.f = f;
  uint32_t u = x.u;
  return (unsigned short)((u + 0x7fffu + ((u >> 16) & 1u)) >> 16);  // RNE
}
static __device__ __forceinline__ float bf2f(unsigned short s) {
  union { uint32_t u; float f; } x; x.u = ((uint32_t)s) << 16; return x.f;
}
static __device__ __forceinline__ float sigf(float x) {
  return 1.f / (1.f + __expf(-x));
}
static __device__ __forceinline__ float tanh_fast(float x) {
  float e = __expf(2.f * x);          // large |x| saturates correctly (inf/0)
  return 1.f - 2.f / (e + 1.f);
}

// ---------------- workspace layout (bytes) ----------------
// lstm B-pack : [c(8)][t(24)][n(16)][lane(64)][j(8)] bf16   k = 32t+8(l>>4)+j
//               k<256 -> W_ih[grow][k], k>=256 -> W_hh[grow][k-256]
//               grow = (n&3)*512 + c*64 + (n>>2)*16 + (l&15)
#define WS_LSTMPK 0
#define WS_LSTMPK_ELEMS 1572864
#define WS_AFFPK 3145728            // [t(16)][lane(64)][j(8)] bf16, col=l&15 (<6)
#define WS_AFFPK_ELEMS 8192
#define WS_DECPK 3162112            // [L(4)][t(8)][n(16)][lane(64)][j(8)] bf16
#define WS_DECPK_ELEMS 262144
#define WS_DSCALE 3686400           // [L(4)][256] f32 : g/||v||
#define WS_TOTAL 3690496

// ---------------- LDS layout (bytes) ----------------
#define OFF_H     0         // 64 x 512 bf16, row stride 1024B, XOR-swizzled
#define OFF_CODE  65536     // 64 x 256 bf16, row stride 512B, XOR-swizzled
#define OFF_BIASP 98304     // 2048 f32 (b_ih+b_hh, permuted gate order)
#define OFF_WIHX  106496    // 2048 x 3 f32 (xyz columns of W_ih, permuted)
#define OFF_XYZ   131072    // 64 x 4 f32
#define OFF_A     132096    // 64 x 8 f32 (affine outputs a[0..5])
#define OFF_W0N   134144    // 256 x 3 f32 (normalized decoder layer-0 weights)
#define OFF_B0    137216    // 256 f32
#define OFF_DB    138240    // 4 x 256 f32 (b1..b4)
#define OFF_W5    142336    // 256 f32
#define OFF_MISC  143360    // [0..5]=b_aff, [6]=b5
#define SMEM_BYTES 143424

// ============================================================================
// prep 1: per-row g/||v|| for decoder layers 1..4
// ============================================================================
__global__ void dec_norm_kernel(const float* __restrict__ v1, const float* __restrict__ v2,
                                const float* __restrict__ v3, const float* __restrict__ v4,
                                const float* __restrict__ g1, const float* __restrict__ g2,
                                const float* __restrict__ g3, const float* __restrict__ g4,
                                float* __restrict__ dscale) {
  int L = blockIdx.x;
  int row = threadIdx.x;
  const float* v = (L == 0) ? v1 : (L == 1) ? v2 : (L == 2) ? v3 : v4;
  const float* g = (L == 0) ? g1 : (L == 1) ? g2 : (L == 2) ? g3 : g4;
  float s = 0.f;
  for (int k = 0; k < 256; ++k) { float x = v[row * 256 + k]; s += x * x; }
  dscale[L * 256 + row] = g[row] / sqrtf(s);
}

// ============================================================================
// prep 2: fragment-major bf16 weight packs
// ============================================================================
__global__ void pack_kernel(const float* __restrict__ W_ih, const float* __restrict__ W_hh,
                            const float* __restrict__ W_aff,
                            const float* __restrict__ v1, const float* __restrict__ v2,
                            const float* __restrict__ v3, const float* __restrict__ v4,
                            const float* __restrict__ dscale,
                            unsigned short* __restrict__ lstmpk,
                            unsigned short* __restrict__ affpk,
                            unsigned short* __restrict__ decpk) {
  int i = blockIdx.x * 256 + threadIdx.x;
  if (i < WS_LSTMPK_ELEMS) {
    int j = i & 7; int rest = i >> 3;
    int l = rest & 63; rest >>= 6;
    int n = rest & 15; rest >>= 4;
    int t = rest % 24; int c = rest / 24;
    int k = 32 * t + 8 * (l >> 4) + j;
    int grow = (n & 3) * 512 + c * 64 + (n >> 2) * 16 + (l & 15);
    float val = (k < 256) ? W_ih[(size_t)grow * 259 + k]
                          : W_hh[(size_t)grow * 512 + (k - 256)];
    lstmpk[i] = f2bf(val);
  } else if (i < WS_LSTMPK_ELEMS + WS_AFFPK_ELEMS) {
    int ii = i - WS_LSTMPK_ELEMS;
    int j = ii & 7, l = (ii >> 3) & 63, t = ii >> 9;
    int k = 32 * t + 8 * (l >> 4) + j;
    int col = l & 15;
    float val = (col < 6) ? W_aff[col * 512 + k] : 0.f;
    affpk[ii] = f2bf(val);
  } else {
    int ii = i - (WS_LSTMPK_ELEMS + WS_AFFPK_ELEMS);  // < 262144
    int j = ii & 7, l = (ii >> 3) & 63, n = (ii >> 9) & 15, t = (ii >> 13) & 7, L = ii >> 16;
    int k = 32 * t + 8 * (l >> 4) + j;
    int col = 16 * n + (l & 15);
    const float* v = (L == 0) ? v1 : (L == 1) ? v2 : (L == 2) ? v3 : v4;
    float val = v[col * 256 + k] * dscale[L * 256 + col];
    decpk[ii] = f2bf(val);
  }
}

// ============================================================================
// main fused kernel: 1024 blocks x 512 threads, 64 rows/block
// ============================================================================
__global__ __launch_bounds__(512, 2) void lstm_main(
    const float* __restrict__ input,
    const float* __restrict__ W_ih,
    const float* __restrict__ b_ih, const float* __restrict__ b_hh,
    const float* __restrict__ b_aff,
    const float* __restrict__ v0, const float* __restrict__ g0, const float* __restrict__ b0,
    const float* __restrict__ b1, const float* __restrict__ b2,
    const float* __restrict__ b3, const float* __restrict__ b4,
    const float* __restrict__ W5, const float* __restrict__ b5,
    const unsigned short* __restrict__ lstmpk,
    const unsigned short* __restrict__ affpk,
    const unsigned short* __restrict__ decpk,
    float* __restrict__ out) {
  extern __shared__ char smem[];
  float* smf = (float*)smem;

  const int tid = threadIdx.x;
  const int lane = tid & 63;
  const int wid = tid >> 6;
  const int l15 = lane & 15;
  const int lg = lane >> 4;            // 0..3
  const int rowg = wid & 3;            // row group (16 rows each)
  const int colh = wid >> 2;           // column half
  const int r0 = blockIdx.x * 64;

  const int arow = rowg * 16 + l15;    // A-fragment row for this lane
  const uint32_t a_sw = (uint32_t)((arow & 7) << 4);
  const uint32_t codebase = OFF_CODE + (uint32_t)arow * 512;
  const uint32_t hbase = OFF_H + (uint32_t)arow * 1024;

  // ---------------- load / build LDS-resident state ----------------
  // code tile -> bf16, swizzled
  {
    int row = tid >> 3;
    int kb0 = (tid & 7) * 8;
    const float* src0 = input + (size_t)(r0 + row) * 259;
#pragma unroll
    for (int it = 0; it < 4; ++it) {
      int kb = kb0 + it * 64;
      const float* src = src0 + kb;
      uint32_t p[4];
#pragma unroll
      for (int jj = 0; jj < 4; ++jj) {
        float f0 = src[2 * jj], f1 = src[2 * jj + 1];
        p[jj] = (uint32_t)f2bf(f0) | ((uint32_t)f2bf(f1) << 16);
      }
      uint32_t byteoff = OFF_CODE + (uint32_t)row * 512 + (uint32_t)(((kb * 2)) ^ ((row & 7) << 4));
      *(uint4*)(smem + byteoff) = make_uint4(p[0], p[1], p[2], p[3]);
    }
  }
  if (tid < 192) {
    int row = tid / 3, d = tid - row * 3;
    smf[OFF_XYZ / 4 + row * 4 + d] = input[(size_t)(r0 + row) * 259 + 256 + d];
  }
  for (int i = tid; i < 2048; i += 512) {
    int c = i >> 8, jc = i & 255, n = jc >> 4, t15 = jc & 15;
    int grow = (n & 3) * 512 + c * 64 + (n >> 2) * 16 + t15;
    smf[OFF_BIASP / 4 + i] = b_ih[grow] + b_hh[grow];
    const float* wr = W_ih + (size_t)grow * 259 + 256;
    smf[OFF_WIHX / 4 + i * 3 + 0] = wr[0];
    smf[OFF_WIHX / 4 + i * 3 + 1] = wr[1];
    smf[OFF_WIHX / 4 + i * 3 + 2] = wr[2];
  }
  if (tid < 256) {
    int u = tid;
    float a0 = v0[u * 3 + 0], a1 = v0[u * 3 + 1], a2 = v0[u * 3 + 2];
    float sc = g0[u] / sqrtf(a0 * a0 + a1 * a1 + a2 * a2);
    smf[OFF_W0N / 4 + u * 3 + 0] = a0 * sc;
    smf[OFF_W0N / 4 + u * 3 + 1] = a1 * sc;
    smf[OFF_W0N / 4 + u * 3 + 2] = a2 * sc;
    smf[OFF_B0 / 4 + u] = b0[u];
    smf[OFF_DB / 4 + 0 * 256 + u] = b1[u];
    smf[OFF_DB / 4 + 1 * 256 + u] = b2[u];
    smf[OFF_DB / 4 + 2 * 256 + u] = b3[u];
    smf[OFF_DB / 4 + 3 * 256 + u] = b4[u];
    smf[OFF_W5 / 4 + u] = W5[u];
  }
  if (tid < 6) smf[OFF_MISC / 4 + tid] = b_aff[tid];
  if (tid == 6) smf[OFF_MISC / 4 + 6] = b5[0];
  __syncthreads();

  // persistent per-thread LSTM cell state (statically indexed -> registers)
  float creg[8][8];
#pragma unroll
  for (int c = 0; c < 8; ++c)
#pragma unroll
    for (int e = 0; e < 8; ++e) creg[c][e] = 0.f;
  uint32_t hst[8][4];  // staged new-h (bf16 packed) until barrier

  const v8s* lp8 = (const v8s*)lstmpk;
  const v8s* ap8 = (const v8s*)affpk;
  const v8s* dp8 = (const v8s*)decpk;

  // ======================= 8 LSTM steps =======================
  for (int step = 0; step < 8; ++step) {
    float xy[4][3];
#pragma unroll
    for (int j = 0; j < 4; ++j) {
      int rr = rowg * 16 + lg * 4 + j;
      xy[j][0] = smf[OFF_XYZ / 4 + rr * 4 + 0];
      xy[j][1] = smf[OFF_XYZ / 4 + rr * 4 + 1];
      xy[j][2] = smf[OFF_XYZ / 4 + rr * 4 + 2];
    }
#pragma unroll
    for (int c = 0; c < 8; ++c) {
      v4f acc[8];
      // init: bias + xyz * W_ihx
#pragma unroll
      for (int fi = 0; fi < 8; ++fi) {
        int coli = c * 256 + (colh * 8 + fi) * 16 + l15;
        float bb = smf[OFF_BIASP / 4 + coli];
        float w0 = smf[OFF_WIHX / 4 + coli * 3 + 0];
        float w1 = smf[OFF_WIHX / 4 + coli * 3 + 1];
        float w2 = smf[OFF_WIHX / 4 + coli * 3 + 2];
#pragma unroll
        for (int j = 0; j < 4; ++j)
          acc[fi][j] = bb + w0 * xy[j][0] + w1 * xy[j][1] + w2 * xy[j][2];
      }
      const v8s* bp = lp8 + (size_t)(c * 24) * 16 * 64;
      // K part 1: code (k=0..255)
#pragma unroll 2
      for (int t = 0; t < 8; ++t) {
        v8s af = *(const v8s*)(smem + codebase + (uint32_t)(((t * 32 + lg * 8) * 2) ^ (int)a_sw));
#pragma unroll
        for (int fi = 0; fi < 8; ++fi) {
          v8s bf = bp[(t * 16 + colh * 8 + fi) * 64 + lane];
          acc[fi] = MFMA16(af, bf, acc[fi]);
        }
      }
      // K part 2: h (k=256..767), skipped at step 0 (h==0)
      if (step > 0) {
#pragma unroll 2
        for (int t2 = 0; t2 < 16; ++t2) {
          v8s af = *(const v8s*)(smem + hbase + (uint32_t)(((t2 * 32 + lg * 8) * 2) ^ (int)a_sw));
#pragma unroll
          for (int fi = 0; fi < 8; ++fi) {
            v8s bf = bp[((t2 + 8) * 16 + colh * 8 + fi) * 64 + lane];
            acc[fi] = MFMA16(af, bf, acc[fi]);
          }
        }
      }
      // lane-local cell update (gate quadruple lives in frags 4m..4m+3)
#pragma unroll
      for (int m = 0; m < 2; ++m) {
        uint32_t plo = 0, phi = 0;
#pragma unroll
        for (int j = 0; j < 4; ++j) {
          float gi = acc[4 * m + 0][j];
          float gf = acc[4 * m + 1][j];
          float gg = acc[4 * m + 2][j];
          float go = acc[4 * m + 3][j];
          float cc = creg[c][m * 4 + j];
          cc = sigf(gf) * cc + sigf(gi) * tanh_fast(gg);
          creg[c][m * 4 + j] = cc;
          float hh = sigf(go) * tanh_fast(cc);
          uint32_t hb = f2bf(hh);
          if (j < 2) plo |= hb << (16 * j); else phi |= hb << (16 * (j - 2));
        }
        hst[c][m * 2 + 0] = plo;
        hst[c][m * 2 + 1] = phi;
      }
    }
    __syncthreads();  // all reads of h_old complete
    // write new h (bf16, swizzled, natural unit order)
#pragma unroll
    for (int c = 0; c < 8; ++c)
#pragma unroll
      for (int m = 0; m < 2; ++m)
#pragma unroll
        for (int j = 0; j < 4; ++j) {
          int u = c * 64 + (colh * 2 + m) * 16 + l15;
          int rr = rowg * 16 + lg * 4 + j;
          uint32_t val = ((j < 2) ? (hst[c][m * 2] >> (16 * j)) : (hst[c][m * 2 + 1] >> (16 * (j - 2)))) & 0xffffu;
          *(unsigned short*)(smem + OFF_H + (uint32_t)rr * 1024 +
                             (uint32_t)(((u * 2)) ^ ((rr & 7) << 4))) = (unsigned short)val;
        }
    __syncthreads();
    // a = h @ W_aff^T + b_aff  (waves 0..3; zero-padded 64x16 MFMA strip)
    if (colh == 0) {
      v4f a1 = {0.f, 0.f, 0.f, 0.f};
#pragma unroll 2
      for (int t = 0; t < 16; ++t) {
        v8s af = *(const v8s*)(smem + hbase + (uint32_t)(((t * 32 + lg * 8) * 2) ^ (int)a_sw));
        v8s bf = ap8[t * 64 + lane];
        a1 = MFMA16(af, bf, a1);
      }
      if (l15 < 6) {
        float ba = smf[OFF_MISC / 4 + l15];
#pragma unroll
        for (int j = 0; j < 4; ++j) {
          int rr = rowg * 16 + lg * 4 + j;
          smf[OFF_A / 4 + rr * 8 + l15] = a1[j] + ba;
        }
      }
    }
    __syncthreads();
    // xyz = a[3:] + (1 + a[:3]) * xyz
    if (tid < 192) {
      int rr = tid / 3, d = tid - rr * 3;
      float ad = smf[OFF_A / 4 + rr * 8 + d];
      float a3 = smf[OFF_A / 4 + rr * 8 + 3 + d];
      float old = smf[OFF_XYZ / 4 + rr * 4 + d];
      smf[OFF_XYZ / 4 + rr * 4 + d] = a3 + (1.f + ad) * old;
    }
    __syncthreads();
  }

  // ======================= decoder =======================
  // layer 0: 3 -> 256 (VALU), write xA = OFF_H
  {
    int row = tid & 63;
    int ublk = tid >> 6;
    float p0 = smf[OFF_XYZ / 4 + row * 4 + 0];
    float p1 = smf[OFF_XYZ / 4 + row * 4 + 1];
    float p2 = smf[OFF_XYZ / 4 + row * 4 + 2];
#pragma unroll
    for (int gq = 0; gq < 4; ++gq) {
      int u0 = ublk * 32 + gq * 8;
      uint32_t pk[4];
#pragma unroll
      for (int jj = 0; jj < 8; ++jj) {
        int uu = u0 + jj;
        float val = smf[OFF_B0 / 4 + uu]
                  + smf[OFF_W0N / 4 + uu * 3 + 0] * p0
                  + smf[OFF_W0N / 4 + uu * 3 + 1] * p1
                  + smf[OFF_W0N / 4 + uu * 3 + 2] * p2;
        val = fmaxf(val, 0.f);
        ((unsigned short*)pk)[jj] = f2bf(val);
      }
      *(uint4*)(smem + OFF_H + (uint32_t)row * 512 +
                (uint32_t)(((u0 * 2)) ^ ((row & 7) << 4))) = *(uint4*)pk;
    }
  }
  __syncthreads();
  // layers 1..4: 256 -> 256 MFMA, ping-pong xA/xB
#pragma unroll
  for (int L = 0; L < 4; ++L) {
    uint32_t xin = OFF_H + (uint32_t)((L & 1) * 32768);
    uint32_t xout = OFF_H + (uint32_t)(((L + 1) & 1) * 32768);
    v4f acc[8];
#pragma unroll
    for (int fi = 0; fi < 8; ++fi) {
      int coli = (colh * 8 + fi) * 16 + l15;
      float bb = smf[OFF_DB / 4 + L * 256 + coli];
      acc[fi][0] = bb; acc[fi][1] = bb; acc[fi][2] = bb; acc[fi][3] = bb;
    }
    uint32_t abase = xin + (uint32_t)arow * 512;
#pragma unroll 2
    for (int t = 0; t < 8; ++t) {
      v8s af = *(const v8s*)(smem + abase + (uint32_t)(((t * 32 + lg * 8) * 2) ^ (int)a_sw));
#pragma unroll
      for (int fi = 0; fi < 8; ++fi) {
        v8s bf = dp8[((L * 8 + t) * 16 + colh * 8 + fi) * 64 + lane];
        acc[fi] = MFMA16(af, bf, acc[fi]);
      }
    }
#pragma unroll
    for (int fi = 0; fi < 8; ++fi) {
      int coli = (colh * 8 + fi) * 16 + l15;
#pragma unroll
      for (int j = 0; j < 4; ++j) {
        int rr = rowg * 16 + lg * 4 + j;
        float v = fmaxf(acc[fi][j], 0.f);
        *(unsigned short*)(smem + xout + (uint32_t)rr * 512 +
                           (uint32_t)(((coli * 2)) ^ ((rr & 7) << 4))) = f2bf(v);
      }
    }
    __syncthreads();
  }
  // layer 5: 256 -> 1 (wave dot + butterfly reduce); final x is at OFF_H
  {
    float b5v = smf[OFF_MISC / 4 + 6];
    for (int rr = 0; rr < 8; ++rr) {
      int r = wid * 8 + rr;
      uint32_t byteoff = OFF_H + (uint32_t)r * 512 + (uint32_t)((lane * 8) ^ ((r & 7) << 4));
      uint2 xv = *(const uint2*)(smem + byteoff);
      float p = 0.f;
#pragma unroll
      for (int jj = 0; jj < 4; ++jj) {
        unsigned short us = (unsigned short)(((jj < 2) ? (xv.x >> (16 * jj)) : (xv.y >> (16 * (jj - 2)))) & 0xffffu);
        p += bf2f(us) * smf[OFF_W5 / 4 + lane * 4 + jj];
      }
#pragma unroll
      for (int off = 32; off >= 1; off >>= 1) p += __shfl_xor(p, off, 64);
      if (lane == 0) out[r0 + r] = p + b5v;
    }
  }
}

// ============================================================================
extern "C" void kernel_launch(void* const* d_in, const int* in_sizes, int n_in,
                              void* d_out, int out_size, void* d_ws, size_t ws_size,
                              hipStream_t stream) {
  const float* input = (const float*)d_in[0];
  const float* W_ih  = (const float*)d_in[1];
  const float* b_ih  = (const float*)d_in[2];
  const float* W_hh  = (const float*)d_in[3];
  const float* b_hh  = (const float*)d_in[4];
  const float* W_aff = (const float*)d_in[5];
  const float* b_aff = (const float*)d_in[6];
  const float* v0 = (const float*)d_in[7];
  const float* g0 = (const float*)d_in[8];
  const float* b0 = (const float*)d_in[9];
  const float* v1 = (const float*)d_in[10];
  const float* g1 = (const float*)d_in[11];
  const float* b1 = (const float*)d_in[12];
  const float* v2 = (const float*)d_in[13];
  const float* g2 = (const float*)d_in[14];
  const float* b2 = (const float*)d_in[15];
  const float* v3 = (const float*)d_in[16];
  const float* g3 = (const float*)d_in[17];
  const float* b3 = (const float*)d_in[18];
  const float* v4 = (const float*)d_in[19];
  const float* g4 = (const float*)d_in[20];
  const float* b4 = (const float*)d_in[21];
  const float* W5 = (const float*)d_in[22];
  const float* b5 = (const float*)d_in[23];

  char* ws = (char*)d_ws;
  unsigned short* lstmpk = (unsigned short*)(ws + WS_LSTMPK);
  unsigned short* affpk  = (unsigned short*)(ws + WS_AFFPK);
  unsigned short* decpk  = (unsigned short*)(ws + WS_DECPK);
  float* dscale = (float*)(ws + WS_DSCALE);
  float* outp = (float*)d_out;

  (void)in_sizes; (void)n_in; (void)out_size; (void)ws_size;

  hipFuncSetAttribute((const void*)lstm_main,
                      hipFuncAttributeMaxDynamicSharedMemorySize, SMEM_BYTES);

  dec_norm_kernel<<<4, 256, 0, stream>>>(v1, v2, v3, v4, g1, g2, g3, g4, dscale);
  pack_kernel<<<7200, 256, 0, stream>>>(W_ih, W_hh, W_aff, v1, v2, v3, v4, dscale,
                                        lstmpk, affpk, decpk);
  lstm_main<<<1024, 512, SMEM_BYTES, stream>>>(
      input, W_ih, b_ih, b_hh, b_aff, v0, g0, b0, b1, b2, b3, b4, W5, b5,
      lstmpk, affpk, decpk, outp);
}

// Round 3
// 4223.070 us; speedup vs baseline: 3.3314x; 3.3314x over previous
//
#include <hip/hip_runtime.h>
#include <stdint.h>

// ============================================================================
// Decoder_24799141167169: 8-step LSTM warp + 5-layer weight-normed SDF decoder
// v3: v2 with ring-slot race fixed (rs starts at 2: prologue owns slots 0,1),
// plus s_setprio around MFMA clusters. B staged via global_load_lds ring-3,
// counted vmcnt(2) + raw barriers; wave grid 2x4; code A-frags in VGPRs;
// xyz folded into K as padded k-tile.
// ============================================================================

typedef short v8s __attribute__((ext_vector_type(8)));
typedef float v4f __attribute__((ext_vector_type(4)));

#define MFMA16(a, b, c) __builtin_amdgcn_mfma_f32_16x16x32_bf16((a), (b), (c), 0, 0, 0)

static __device__ __forceinline__ unsigned short f2bf(float f) {
  union { float f; uint32_t u; } x; x.f = f;
  uint32_t u = x.u;
  return (unsigned short)((u + 0x7fffu + ((u >> 16) & 1u)) >> 16);  // RNE
}
static __device__ __forceinline__ float bf2f(unsigned short s) {
  union { uint32_t u; float f; } x; x.u = ((uint32_t)s) << 16; return x.f;
}
static __device__ __forceinline__ float sigf(float x) {
  return 1.f / (1.f + __expf(-x));
}
static __device__ __forceinline__ float tanh_fast(float x) {
  float e = __expf(2.f * x);
  return 1.f - 2.f / (e + 1.f);
}

static __device__ __forceinline__ void gload16(const void* g, void* l) {
  __builtin_amdgcn_global_load_lds(
      (const __attribute__((address_space(1))) uint32_t*)g,
      (__attribute__((address_space(3))) uint32_t*)l, 16, 0, 0);
}

// ---------------- workspace layout (bytes) ----------------
// lstm B-pack: [c(8)][tb(25)][fi(16)][lane(64)][j(8)] bf16
//   k = 32*tb' + 8*(l>>4) + j ; tb 0..7 = code cols, tb 8 = xyz (pad to 32),
//   tb 9..24 = h cols (W_hh). grow = (fi&3)*512 + c*64 + (fi>>2)*16 + (l&15)
#define WS_LSTMPK 0
#define WS_LSTMPK_ELEMS 1638400     // 8*25*16*64*8
#define WS_AFFPK 3276800            // [t(16)][lane(64)][j(8)] bf16, col=l&15 (<6)
#define WS_AFFPK_ELEMS 8192
#define WS_DECPK 3293184            // [(L*8+t)(32)][fi(16)][lane(64)][j(8)] bf16
#define WS_DECPK_ELEMS 262144
#define WS_DSCALE 3817472           // [4][256] f32 : g/||v||
#define WS_TOTAL 3821568

// ---------------- LDS layout (bytes) ----------------
#define OFF_H     0         // 64 x 512 bf16, row stride 1024B, XOR-swizzled
#define OFF_RING  65536     // 3 x 16384 B-slab ring
#define OFF_AFF   114688    // 16 KiB resident W_aff pack
#define OFF_BIASP 131072    // 2048 f32 (b_ih+b_hh, permuted gate order)
#define OFF_XYZ   139264    // 64 x 4 f32
#define OFF_A     140288    // 64 x 8 f32
#define OFF_W0N   142336    // 256 x 3 f32
#define OFF_B0    145408    // 256 f32
#define OFF_DB    146432    // 4 x 256 f32
#define OFF_W5    150528    // 256 f32
#define OFF_MISC  151552    // [0..5]=b_aff, [6]=b5
#define SMEM_BYTES 151616

// ============================================================================
__global__ void dec_norm_kernel(const float* __restrict__ v1, const float* __restrict__ v2,
                                const float* __restrict__ v3, const float* __restrict__ v4,
                                const float* __restrict__ g1, const float* __restrict__ g2,
                                const float* __restrict__ g3, const float* __restrict__ g4,
                                float* __restrict__ dscale) {
  int L = blockIdx.x;
  int row = threadIdx.x;
  const float* v = (L == 0) ? v1 : (L == 1) ? v2 : (L == 2) ? v3 : v4;
  const float* g = (L == 0) ? g1 : (L == 1) ? g2 : (L == 2) ? g3 : g4;
  float s = 0.f;
  for (int k = 0; k < 256; ++k) { float x = v[row * 256 + k]; s += x * x; }
  dscale[L * 256 + row] = g[row] / sqrtf(s);
}

// ============================================================================
__global__ void pack_kernel(const float* __restrict__ W_ih, const float* __restrict__ W_hh,
                            const float* __restrict__ W_aff,
                            const float* __restrict__ v1, const float* __restrict__ v2,
                            const float* __restrict__ v3, const float* __restrict__ v4,
                            const float* __restrict__ dscale,
                            unsigned short* __restrict__ lstmpk,
                            unsigned short* __restrict__ affpk,
                            unsigned short* __restrict__ decpk) {
  int i = blockIdx.x * 256 + threadIdx.x;
  if (i < WS_LSTMPK_ELEMS) {
    int j = i & 7; int rest = i >> 3;
    int l = rest & 63; rest >>= 6;
    int fi = rest & 15; rest >>= 4;
    int tb = rest % 25; int c = rest / 25;
    int kl = 8 * (l >> 4) + j;
    int grow = (fi & 3) * 512 + c * 64 + (fi >> 2) * 16 + (l & 15);
    float val;
    if (tb < 8)       val = W_ih[(size_t)grow * 259 + tb * 32 + kl];
    else if (tb == 8) val = (kl < 3) ? W_ih[(size_t)grow * 259 + 256 + kl] : 0.f;
    else              val = W_hh[(size_t)grow * 512 + (tb - 9) * 32 + kl];
    lstmpk[i] = f2bf(val);
  } else if (i < WS_LSTMPK_ELEMS + WS_AFFPK_ELEMS) {
    int ii = i - WS_LSTMPK_ELEMS;
    int j = ii & 7, l = (ii >> 3) & 63, t = ii >> 9;
    int k = 32 * t + 8 * (l >> 4) + j;
    int col = l & 15;
    float val = (col < 6) ? W_aff[col * 512 + k] : 0.f;
    affpk[ii] = f2bf(val);
  } else {
    int ii = i - (WS_LSTMPK_ELEMS + WS_AFFPK_ELEMS);  // < 262144
    int j = ii & 7, l = (ii >> 3) & 63, fi = (ii >> 9) & 15, t = (ii >> 13) & 7, L = ii >> 16;
    int k = 32 * t + 8 * (l >> 4) + j;
    int col = 16 * fi + (l & 15);
    const float* v = (L == 0) ? v1 : (L == 1) ? v2 : (L == 2) ? v3 : v4;
    float val = v[col * 256 + k] * dscale[L * 256 + col];
    decpk[ii] = f2bf(val);
  }
}

// ============================================================================
// main fused kernel: 1024 blocks x 512 threads, 64 rows/block
// wave grid: rowg = wid&1 (32 rows), colq = wid>>1 (64 cols per 256-col chunk)
// ============================================================================
__global__ __launch_bounds__(512, 1) void lstm_main(
    const float* __restrict__ input,
    const float* __restrict__ b_ih, const float* __restrict__ b_hh,
    const float* __restrict__ b_aff,
    const float* __restrict__ v0, const float* __restrict__ g0, const float* __restrict__ b0,
    const float* __restrict__ b1, const float* __restrict__ b2,
    const float* __restrict__ b3, const float* __restrict__ b4,
    const float* __restrict__ W5, const float* __restrict__ b5,
    const unsigned short* __restrict__ lstmpk,
    const unsigned short* __restrict__ affpk,
    const unsigned short* __restrict__ decpk,
    float* __restrict__ out) {
  extern __shared__ char smem[];
  float* smf = (float*)smem;

  const int tid = threadIdx.x;
  const int lane = tid & 63;
  const int wid = tid >> 6;
  const int l15 = lane & 15;
  const int lg = lane >> 4;            // 0..3
  const int rowg = wid & 1;            // row group (32 rows)
  const int colq = wid >> 1;           // col quarter (64 cols per chunk)
  const int r0 = blockIdx.x * 64;

  const int arow0 = rowg * 32 + l15;
  const int arow1 = arow0 + 16;
  const uint32_t a_sw = (uint32_t)((l15 & 7) << 4);
  const uint32_t hbase0 = OFF_H + (uint32_t)arow0 * 1024;
  const uint32_t hbase1 = OFF_H + (uint32_t)arow1 * 1024;
  const char* lstm_c = (const char*)lstmpk;
  const char* dec_c = (const char*)decpk;

  // ---------------- init LDS ----------------
  {  // zero h (step 0 reads it as A with zero contribution)
    uint4 z = make_uint4(0, 0, 0, 0);
    for (int i = tid; i < 4096; i += 512) *(uint4*)(smem + OFF_H + (size_t)i * 16) = z;
  }
  if (tid < 192) {
    int row = tid / 3, d = tid - row * 3;
    smf[OFF_XYZ / 4 + row * 4 + d] = input[(size_t)(r0 + row) * 259 + 256 + d];
  }
  for (int i = tid; i < 2048; i += 512) {
    int c = i >> 8, jc = i & 255, n = jc >> 4, t15 = jc & 15;
    int grow = (n & 3) * 512 + c * 64 + (n >> 2) * 16 + t15;
    smf[OFF_BIASP / 4 + i] = b_ih[grow] + b_hh[grow];
  }
  if (tid < 256) {
    int u = tid;
    float a0 = v0[u * 3 + 0], a1 = v0[u * 3 + 1], a2 = v0[u * 3 + 2];
    float sc = g0[u] / sqrtf(a0 * a0 + a1 * a1 + a2 * a2);
    smf[OFF_W0N / 4 + u * 3 + 0] = a0 * sc;
    smf[OFF_W0N / 4 + u * 3 + 1] = a1 * sc;
    smf[OFF_W0N / 4 + u * 3 + 2] = a2 * sc;
    smf[OFF_B0 / 4 + u] = b0[u];
    smf[OFF_DB / 4 + 0 * 256 + u] = b1[u];
    smf[OFF_DB / 4 + 1 * 256 + u] = b2[u];
    smf[OFF_DB / 4 + 2 * 256 + u] = b3[u];
    smf[OFF_DB / 4 + 3 * 256 + u] = b4[u];
    smf[OFF_W5 / 4 + u] = W5[u];
  }
  if (tid < 6) smf[OFF_MISC / 4 + tid] = b_aff[tid];
  if (tid == 6) smf[OFF_MISC / 4 + 6] = b5[0];
  {  // stage resident W_aff pack: 16 chunks of 1KB, 2 per wave
    const char* src = (const char*)affpk + (((size_t)(2 * wid)) << 10) + (size_t)lane * 16;
    char* dst = smem + OFF_AFF + ((2 * wid) << 10);
    gload16(src, dst);
    gload16(src + 1024, dst + 1024);
  }

  // code A-fragments: persistent in VGPRs (step- and c-invariant)
  v8s codeA0[8], codeA1[8];
  {
    const float* cr0 = input + (size_t)(r0 + arow0) * 259;
    const float* cr1 = input + (size_t)(r0 + arow1) * 259;
#pragma unroll
    for (int t = 0; t < 8; ++t) {
      v8s a0v = {0, 0, 0, 0, 0, 0, 0, 0}, a1v = {0, 0, 0, 0, 0, 0, 0, 0};
#pragma unroll
      for (int j = 0; j < 8; ++j) {
        a0v[j] = (short)f2bf(cr0[t * 32 + lg * 8 + j]);
        a1v[j] = (short)f2bf(cr1[t * 32 + lg * 8 + j]);
      }
      codeA0[t] = a0v; codeA1[t] = a1v;
    }
  }
  __syncthreads();   // drains vmcnt(0): W_aff pack resident from here on

  // persistent cell state + staged h
  float creg[8][8];
#pragma unroll
  for (int c = 0; c < 8; ++c)
#pragma unroll
    for (int e = 0; e < 8; ++e) creg[c][e] = 0.f;
  uint32_t hst[8][4];

  // ======================= 8 LSTM steps =======================
  for (int step = 0; step < 8; ++step) {
    // xyz A-fragment (k-tile 8: real k = 0..2 only, lg==0 lanes)
    v8s xyzA0 = {0, 0, 0, 0, 0, 0, 0, 0}, xyzA1 = {0, 0, 0, 0, 0, 0, 0, 0};
    if (lg == 0) {
      xyzA0[0] = (short)f2bf(smf[OFF_XYZ / 4 + arow0 * 4 + 0]);
      xyzA0[1] = (short)f2bf(smf[OFF_XYZ / 4 + arow0 * 4 + 1]);
      xyzA0[2] = (short)f2bf(smf[OFF_XYZ / 4 + arow0 * 4 + 2]);
      xyzA1[0] = (short)f2bf(smf[OFF_XYZ / 4 + arow1 * 4 + 0]);
      xyzA1[1] = (short)f2bf(smf[OFF_XYZ / 4 + arow1 * 4 + 1]);
      xyzA1[2] = (short)f2bf(smf[OFF_XYZ / 4 + arow1 * 4 + 2]);
    }

    // ---- phase machinery: ring-3 B slabs, 200 phases (8c x 25tb) ----
    // prologue staged phases 0,1 -> ring slots 0,1; body of phase p stages
    // phase p+2 -> slot (p+2)%3, so rs MUST start at 2 (v2 bug: rs=0 raced).
    int cs = 0, tbs = 0, rs = 2, sb = 0;
    {  // prologue: stage slabs for phase 0,1
      const char* s0 = lstm_c + (((size_t)(2 * wid)) << 10) + (size_t)lane * 16;
      char* d0 = smem + OFF_RING + ((2 * wid) << 10);
      gload16(s0, d0); gload16(s0 + 1024, d0 + 1024);
      const char* s1 = lstm_c + (((size_t)(16 + 2 * wid)) << 10) + (size_t)lane * 16;
      char* d1 = smem + OFF_RING + 16384 + ((2 * wid) << 10);
      gload16(s1, d1); gload16(s1 + 1024, d1 + 1024);
      tbs = 2;
    }

#pragma unroll
    for (int c = 0; c < 8; ++c) {
      v4f acc0[4], acc1[4];
#pragma unroll
      for (int fi = 0; fi < 4; ++fi) {
        float bb = smf[OFF_BIASP / 4 + c * 256 + (colq * 4 + fi) * 16 + l15];
        acc0[fi][0] = bb; acc0[fi][1] = bb; acc0[fi][2] = bb; acc0[fi][3] = bb;
        acc1[fi][0] = bb; acc1[fi][1] = bb; acc1[fi][2] = bb; acc1[fi][3] = bb;
      }

      auto phase = [&](v8s af0, v8s af1, bool last) {
        if (last) { asm volatile("s_waitcnt vmcnt(0)" ::: "memory"); }
        else      { asm volatile("s_waitcnt vmcnt(2)" ::: "memory"); }
        __builtin_amdgcn_s_barrier();
        if (cs < 8) {
          const char* src = lstm_c + (((size_t)((cs * 25 + tbs) * 16 + 2 * wid)) << 10)
                          + (size_t)lane * 16;
          char* dst = smem + OFF_RING + rs * 16384 + ((2 * wid) << 10);
          gload16(src, dst);
          gload16(src + 1024, dst + 1024);
          rs = (rs == 2) ? 0 : rs + 1;
          if (++tbs == 25) { tbs = 0; ++cs; }
        }
        const char* sl = smem + OFF_RING + sb * 16384 + (colq << 12) + (lane << 4);
        __builtin_amdgcn_s_setprio(1);
#pragma unroll
        for (int fi = 0; fi < 4; ++fi) {
          v8s bf = *(const v8s*)(sl + (fi << 10));
          acc0[fi] = MFMA16(af0, bf, acc0[fi]);
          acc1[fi] = MFMA16(af1, bf, acc1[fi]);
        }
        __builtin_amdgcn_s_setprio(0);
        sb = (sb == 2) ? 0 : sb + 1;
      };

      // code k-tiles (A from registers)
#pragma unroll
      for (int t = 0; t < 8; ++t) phase(codeA0[t], codeA1[t], false);
      // xyz k-tile
      phase(xyzA0, xyzA1, false);
      // h k-tiles (A from swizzled h LDS)
#pragma unroll 2
      for (int t2 = 0; t2 < 16; ++t2) {
        uint32_t ko = (uint32_t)(t2 * 32 + lg * 8) * 2;
        v8s af0 = *(const v8s*)(smem + hbase0 + (ko ^ a_sw));
        v8s af1 = *(const v8s*)(smem + hbase1 + (ko ^ a_sw));
        phase(af0, af1, (c == 7) && (t2 == 15));
      }

      // lane-local cell update: gates for unit u = c*64+colq*16+l15 are acc[0..3]
#define CELLUP(AQ, M) do {                                                   \
        uint32_t plo = 0, phi = 0;                                           \
        _Pragma("unroll")                                                    \
        for (int j = 0; j < 4; ++j) {                                        \
          float gi = AQ[0][j], gf = AQ[1][j], gg = AQ[2][j], go = AQ[3][j];  \
          float cc = creg[c][(M) * 4 + j];                                   \
          cc = sigf(gf) * cc + sigf(gi) * tanh_fast(gg);                     \
          creg[c][(M) * 4 + j] = cc;                                         \
          uint32_t hb = f2bf(sigf(go) * tanh_fast(cc));                      \
          if (j < 2) plo |= hb << (16 * j); else phi |= hb << (16 * (j - 2));\
        }                                                                    \
        hst[c][(M) * 2 + 0] = plo; hst[c][(M) * 2 + 1] = phi; } while (0)
      CELLUP(acc0, 0);
      CELLUP(acc1, 1);
#undef CELLUP
    }

    __syncthreads();  // all h_old reads complete
    // write new h (bf16, swizzled)
#pragma unroll
    for (int c = 0; c < 8; ++c)
#pragma unroll
      for (int m = 0; m < 2; ++m)
#pragma unroll
        for (int j = 0; j < 4; ++j) {
          int u = c * 64 + colq * 16 + l15;
          int rr = rowg * 32 + m * 16 + lg * 4 + j;
          uint32_t val = ((j < 2) ? (hst[c][m * 2] >> (16 * j))
                                  : (hst[c][m * 2 + 1] >> (16 * (j - 2)))) & 0xffffu;
          *(unsigned short*)(smem + OFF_H + (uint32_t)rr * 1024 +
                             (uint32_t)((u * 2) ^ ((rr & 7) << 4))) = (unsigned short)val;
        }
    __syncthreads();
    // a = h @ W_aff^T + b_aff  (waves 0,1 cover all 64 rows)
    if (wid < 2) {
      v4f a0 = {0.f, 0.f, 0.f, 0.f}, a1v = {0.f, 0.f, 0.f, 0.f};
#pragma unroll 2
      for (int t = 0; t < 16; ++t) {
        uint32_t ko = (uint32_t)(t * 32 + lg * 8) * 2;
        v8s bf = *(const v8s*)(smem + OFF_AFF + (t << 10) + (lane << 4));
        v8s af0 = *(const v8s*)(smem + hbase0 + (ko ^ a_sw));
        v8s af1 = *(const v8s*)(smem + hbase1 + (ko ^ a_sw));
        a0 = MFMA16(af0, bf, a0);
        a1v = MFMA16(af1, bf, a1v);
      }
      if (l15 < 6) {
        float ba = smf[OFF_MISC / 4 + l15];
#pragma unroll
        for (int j = 0; j < 4; ++j) {
          smf[OFF_A / 4 + (rowg * 32 + lg * 4 + j) * 8 + l15] = a0[j] + ba;
          smf[OFF_A / 4 + (rowg * 32 + 16 + lg * 4 + j) * 8 + l15] = a1v[j] + ba;
        }
      }
    }
    __syncthreads();
    // xyz = a[3:] + (1 + a[:3]) * xyz
    if (tid < 192) {
      int rr = tid / 3, d = tid - rr * 3;
      float ad = smf[OFF_A / 4 + rr * 8 + d];
      float a3 = smf[OFF_A / 4 + rr * 8 + 3 + d];
      float old = smf[OFF_XYZ / 4 + rr * 4 + d];
      smf[OFF_XYZ / 4 + rr * 4 + d] = a3 + (1.f + ad) * old;
    }
    __syncthreads();
  }

  // ======================= decoder =======================
  // stage first 2 decoder slabs early (the layer-0 __syncthreads will drain
  // them; ring slots 0,1 are free — all LSTM ring reads completed)
  {
    const char* s0 = dec_c + (((size_t)(2 * wid)) << 10) + (size_t)lane * 16;
    char* d0 = smem + OFF_RING + ((2 * wid) << 10);
    gload16(s0, d0); gload16(s0 + 1024, d0 + 1024);
    const char* s1 = dec_c + (((size_t)(16 + 2 * wid)) << 10) + (size_t)lane * 16;
    char* d1 = smem + OFF_RING + 16384 + ((2 * wid) << 10);
    gload16(s1, d1); gload16(s1 + 1024, d1 + 1024);
  }
  // layer 0: 3 -> 256 (VALU), write xA at OFF_H
  {
    int row = tid & 63;
    int ublk = tid >> 6;
    float p0 = smf[OFF_XYZ / 4 + row * 4 + 0];
    float p1 = smf[OFF_XYZ / 4 + row * 4 + 1];
    float p2 = smf[OFF_XYZ / 4 + row * 4 + 2];
#pragma unroll
    for (int gq = 0; gq < 4; ++gq) {
      int u0 = ublk * 32 + gq * 8;
      uint32_t pk[4];
#pragma unroll
      for (int jj = 0; jj < 8; ++jj) {
        int uu = u0 + jj;
        float val = smf[OFF_B0 / 4 + uu]
                  + smf[OFF_W0N / 4 + uu * 3 + 0] * p0
                  + smf[OFF_W0N / 4 + uu * 3 + 1] * p1
                  + smf[OFF_W0N / 4 + uu * 3 + 2] * p2;
        val = fmaxf(val, 0.f);
        ((unsigned short*)pk)[jj] = f2bf(val);
      }
      *(uint4*)(smem + OFF_H + (uint32_t)row * 512 +
                (uint32_t)((u0 * 2) ^ ((row & 7) << 4))) = *(uint4*)pk;
    }
  }
  __syncthreads();

  // layers 1..4: 256 -> 256 MFMA, staged B, ping-pong x tiles
  {
    int ps = 2, rs = 2, sb = 0;
#pragma unroll
    for (int L = 0; L < 4; ++L) {
      v4f acc0[4], acc1[4];
#pragma unroll
      for (int fi = 0; fi < 4; ++fi) {
        float bb = smf[OFF_DB / 4 + L * 256 + (colq * 4 + fi) * 16 + l15];
        acc0[fi][0] = bb; acc0[fi][1] = bb; acc0[fi][2] = bb; acc0[fi][3] = bb;
        acc1[fi][0] = bb; acc1[fi][1] = bb; acc1[fi][2] = bb; acc1[fi][3] = bb;
      }
      uint32_t xin = OFF_H + (uint32_t)((L & 1) * 32768);
      uint32_t ab0 = xin + (uint32_t)arow0 * 512;
      uint32_t ab1 = xin + (uint32_t)arow1 * 512;
#pragma unroll
      for (int t = 0; t < 8; ++t) {
        uint32_t ko = (uint32_t)(t * 32 + lg * 8) * 2;
        v8s af0 = *(const v8s*)(smem + ab0 + (ko ^ a_sw));
        v8s af1 = *(const v8s*)(smem + ab1 + (ko ^ a_sw));
        if (L == 3 && t == 7) { asm volatile("s_waitcnt vmcnt(0)" ::: "memory"); }
        else                  { asm volatile("s_waitcnt vmcnt(2)" ::: "memory"); }
        __builtin_amdgcn_s_barrier();
        if (ps < 32) {
          const char* src = dec_c + (((size_t)(ps * 16 + 2 * wid)) << 10) + (size_t)lane * 16;
          char* dst = smem + OFF_RING + rs * 16384 + ((2 * wid) << 10);
          gload16(src, dst);
          gload16(src + 1024, dst + 1024);
          ps++;
          rs = (rs == 2) ? 0 : rs + 1;
        }
        const char* sl = smem + OFF_RING + sb * 16384 + (colq << 12) + (lane << 4);
        __builtin_amdgcn_s_setprio(1);
#pragma unroll
        for (int fi = 0; fi < 4; ++fi) {
          v8s bf = *(const v8s*)(sl + (fi << 10));
          acc0[fi] = MFMA16(af0, bf, acc0[fi]);
          acc1[fi] = MFMA16(af1, bf, acc1[fi]);
        }
        __builtin_amdgcn_s_setprio(0);
        sb = (sb == 2) ? 0 : sb + 1;
      }
      uint32_t xout = OFF_H + (uint32_t)(((L + 1) & 1) * 32768);
#pragma unroll
      for (int fi = 0; fi < 4; ++fi) {
        int coli = (colq * 4 + fi) * 16 + l15;
#pragma unroll
        for (int j = 0; j < 4; ++j) {
          int rr0 = rowg * 32 + lg * 4 + j;
          int rr1 = rr0 + 16;
          *(unsigned short*)(smem + xout + (uint32_t)rr0 * 512 +
                             (uint32_t)((coli * 2) ^ ((rr0 & 7) << 4))) = f2bf(fmaxf(acc0[fi][j], 0.f));
          *(unsigned short*)(smem + xout + (uint32_t)rr1 * 512 +
                             (uint32_t)((coli * 2) ^ ((rr1 & 7) << 4))) = f2bf(fmaxf(acc1[fi][j], 0.f));
        }
      }
      __syncthreads();
    }
  }

  // layer 5: 256 -> 1 (wave dot + butterfly reduce); final x at OFF_H
  {
    float b5v = smf[OFF_MISC / 4 + 6];
    for (int rr = 0; rr < 8; ++rr) {
      int r = wid * 8 + rr;
      uint32_t byteoff = OFF_H + (uint32_t)r * 512 + (uint32_t)((lane * 8) ^ ((r & 7) << 4));
      uint2 xv = *(const uint2*)(smem + byteoff);
      float p = 0.f;
#pragma unroll
      for (int jj = 0; jj < 4; ++jj) {
        unsigned short us = (unsigned short)(((jj < 2) ? (xv.x >> (16 * jj))
                                                       : (xv.y >> (16 * (jj - 2)))) & 0xffffu);
        p += bf2f(us) * smf[OFF_W5 / 4 + lane * 4 + jj];
      }
#pragma unroll
      for (int off = 32; off >= 1; off >>= 1) p += __shfl_xor(p, off, 64);
      if (lane == 0) out[r0 + r] = p + b5v;
    }
  }
}

// ============================================================================
extern "C" void kernel_launch(void* const* d_in, const int* in_sizes, int n_in,
                              void* d_out, int out_size, void* d_ws, size_t ws_size,
                              hipStream_t stream) {
  const float* input = (const float*)d_in[0];
  const float* W_ih  = (const float*)d_in[1];
  const float* b_ih  = (const float*)d_in[2];
  const float* W_hh  = (const float*)d_in[3];
  const float* b_hh  = (const float*)d_in[4];
  const float* W_aff = (const float*)d_in[5];
  const float* b_aff = (const float*)d_in[6];
  const float* v0 = (const float*)d_in[7];
  const float* g0 = (const float*)d_in[8];
  const float* b0 = (const float*)d_in[9];
  const float* v1 = (const float*)d_in[10];
  const float* g1 = (const float*)d_in[11];
  const float* b1 = (const float*)d_in[12];
  const float* v2 = (const float*)d_in[13];
  const float* g2 = (const float*)d_in[14];
  const float* b2 = (const float*)d_in[15];
  const float* v3 = (const float*)d_in[16];
  const float* g3 = (const float*)d_in[17];
  const float* b3 = (const float*)d_in[18];
  const float* v4 = (const float*)d_in[19];
  const float* g4 = (const float*)d_in[20];
  const float* b4 = (const float*)d_in[21];
  const float* W5 = (const float*)d_in[22];
  const float* b5 = (const float*)d_in[23];

  char* ws = (char*)d_ws;
  unsigned short* lstmpk = (unsigned short*)(ws + WS_LSTMPK);
  unsigned short* affpk  = (unsigned short*)(ws + WS_AFFPK);
  unsigned short* decpk  = (unsigned short*)(ws + WS_DECPK);
  float* dscale = (float*)(ws + WS_DSCALE);
  float* outp = (float*)d_out;

  (void)in_sizes; (void)n_in; (void)out_size; (void)ws_size;

  hipFuncSetAttribute((const void*)lstm_main,
                      hipFuncAttributeMaxDynamicSharedMemorySize, SMEM_BYTES);

  dec_norm_kernel<<<4, 256, 0, stream>>>(v1, v2, v3, v4, g1, g2, g3, g4, dscale);
  pack_kernel<<<7456, 256, 0, stream>>>(W_ih, W_hh, W_aff, v1, v2, v3, v4, dscale,
                                        lstmpk, affpk, decpk);
  lstm_main<<<1024, 512, SMEM_BYTES, stream>>>(
      input, b_ih, b_hh, b_aff, v0, g0, b0, b1, b2, b3, b4, W5, b5,
      lstmpk, affpk, decpk, outp);
}

// Round 4
// 3613.672 us; speedup vs baseline: 3.8932x; 1.1686x over previous
//
#include <hip/hip_runtime.h>
#include <stdint.h>

// ============================================================================
// Decoder_24799141167169: 8-step LSTM warp + 5-layer weight-normed SDF decoder
// v4: de-spill (code A-frags in LDS, not VGPR), per-block c-rotation for L2,
// step-0 h-skip, W_aff streamed through ring, cross-step prologue staging.
// Ring-3 B slabs via global_load_lds, uniform vmcnt(2) + raw barriers.
// ============================================================================

typedef short v8s __attribute__((ext_vector_type(8)));
typedef float v4f __attribute__((ext_vector_type(4)));

#define MFMA16(a, b, c) __builtin_amdgcn_mfma_f32_16x16x32_bf16((a), (b), (c), 0, 0, 0)

static __device__ __forceinline__ unsigned short f2bf(float f) {
  union { float f; uint32_t u; } x; x.f = f;
  uint32_t u = x.u;
  return (unsigned short)((u + 0x7fffu + ((u >> 16) & 1u)) >> 16);  // RNE
}
static __device__ __forceinline__ float bf2f(unsigned short s) {
  union { uint32_t u; float f; } x; x.u = ((uint32_t)s) << 16; return x.f;
}
static __device__ __forceinline__ float sigf(float x) {
  return 1.f / (1.f + __expf(-x));
}
static __device__ __forceinline__ float tanh_fast(float x) {
  float e = __expf(2.f * x);
  return 1.f - 2.f / (e + 1.f);
}

static __device__ __forceinline__ void gload16(const void* g, void* l) {
  __builtin_amdgcn_global_load_lds(
      (const __attribute__((address_space(1))) uint32_t*)g,
      (__attribute__((address_space(3))) uint32_t*)l, 16, 0, 0);
}

// ---------------- workspace layout (bytes) ----------------
// lstm B-pack: [c(8)][tb(25)][fi(16)][lane(64)][j(8)] bf16
//   k = 32*tb' + 8*(l>>4) + j ; tb 0..7 = code cols, tb 8 = xyz (pad to 32),
//   tb 9..24 = h cols (W_hh). grow = (fi&3)*512 + c*64 + (fi>>2)*16 + (l&15)
#define WS_LSTMPK 0
#define WS_LSTMPK_ELEMS 1638400     // 8*25*16*64*8
#define WS_AFFPK 3276800            // [t(16)][lane(64)][j(8)] bf16, col=l&15 (<6)
#define WS_AFFPK_ELEMS 8192
#define WS_DECPK 3293184            // [(L*8+t)(32)][fi(16)][lane(64)][j(8)] bf16
#define WS_DECPK_ELEMS 262144
#define WS_DSCALE 3817472           // [4][256] f32 : g/||v||
#define WS_TOTAL 3821568

// ---------------- LDS layout (bytes) ----------------
#define OFF_H     0         // 64 x 512 bf16, row stride 1024B, XOR-swizzled
#define OFF_RING  65536     // 3 x 16384 B-slab ring
#define OFF_CODE  114688    // 64 x 256 bf16, row stride 512B, XOR-swizzled
#define OFF_BIASP 147456    // 2048 bf16 (b_ih+b_hh, permuted; 0/1 exact)
#define OFF_XYZ   151552    // 64 x 4 f32
#define OFF_A     152576    // 64 x 8 f32
#define OFF_W0N   154624    // 256 x 3 bf16
#define OFF_B0    156160    // 256 f32
#define OFF_DB    157184    // 4 x 256 bf16
#define OFF_W5    159232    // 256 f32
#define OFF_MISC  160256    // [0..5]=b_aff, [6]=b5
#define SMEM_BYTES 160288

// ============================================================================
__global__ void dec_norm_kernel(const float* __restrict__ v1, const float* __restrict__ v2,
                                const float* __restrict__ v3, const float* __restrict__ v4,
                                const float* __restrict__ g1, const float* __restrict__ g2,
                                const float* __restrict__ g3, const float* __restrict__ g4,
                                float* __restrict__ dscale) {
  int L = blockIdx.x;
  int row = threadIdx.x;
  const float* v = (L == 0) ? v1 : (L == 1) ? v2 : (L == 2) ? v3 : v4;
  const float* g = (L == 0) ? g1 : (L == 1) ? g2 : (L == 2) ? g3 : g4;
  float s = 0.f;
  for (int k = 0; k < 256; ++k) { float x = v[row * 256 + k]; s += x * x; }
  dscale[L * 256 + row] = g[row] / sqrtf(s);
}

// ============================================================================
__global__ void pack_kernel(const float* __restrict__ W_ih, const float* __restrict__ W_hh,
                            const float* __restrict__ W_aff,
                            const float* __restrict__ v1, const float* __restrict__ v2,
                            const float* __restrict__ v3, const float* __restrict__ v4,
                            const float* __restrict__ dscale,
                            unsigned short* __restrict__ lstmpk,
                            unsigned short* __restrict__ affpk,
                            unsigned short* __restrict__ decpk) {
  int i = blockIdx.x * 256 + threadIdx.x;
  if (i < WS_LSTMPK_ELEMS) {
    int j = i & 7; int rest = i >> 3;
    int l = rest & 63; rest >>= 6;
    int fi = rest & 15; rest >>= 4;
    int tb = rest % 25; int c = rest / 25;
    int kl = 8 * (l >> 4) + j;
    int grow = (fi & 3) * 512 + c * 64 + (fi >> 2) * 16 + (l & 15);
    float val;
    if (tb < 8)       val = W_ih[(size_t)grow * 259 + tb * 32 + kl];
    else if (tb == 8) val = (kl < 3) ? W_ih[(size_t)grow * 259 + 256 + kl] : 0.f;
    else              val = W_hh[(size_t)grow * 512 + (tb - 9) * 32 + kl];
    lstmpk[i] = f2bf(val);
  } else if (i < WS_LSTMPK_ELEMS + WS_AFFPK_ELEMS) {
    int ii = i - WS_LSTMPK_ELEMS;
    int j = ii & 7, l = (ii >> 3) & 63, t = ii >> 9;
    int k = 32 * t + 8 * (l >> 4) + j;
    int col = l & 15;
    float val = (col < 6) ? W_aff[col * 512 + k] : 0.f;
    affpk[ii] = f2bf(val);
  } else {
    int ii = i - (WS_LSTMPK_ELEMS + WS_AFFPK_ELEMS);  // < 262144
    int j = ii & 7, l = (ii >> 3) & 63, fi = (ii >> 9) & 15, t = (ii >> 13) & 7, L = ii >> 16;
    int k = 32 * t + 8 * (l >> 4) + j;
    int col = 16 * fi + (l & 15);
    const float* v = (L == 0) ? v1 : (L == 1) ? v2 : (L == 2) ? v3 : v4;
    float val = v[col * 256 + k] * dscale[L * 256 + col];
    decpk[ii] = f2bf(val);
  }
}

// ============================================================================
// main fused kernel: 1024 blocks x 512 threads, 64 rows/block
// wave grid: rowg = wid&1 (32 rows), colq = wid>>1 (64 cols per 256-col chunk)
// ============================================================================
__global__ __launch_bounds__(512, 1) void lstm_main(
    const float* __restrict__ input,
    const float* __restrict__ b_ih, const float* __restrict__ b_hh,
    const float* __restrict__ b_aff,
    const float* __restrict__ v0, const float* __restrict__ g0, const float* __restrict__ b0,
    const float* __restrict__ b1, const float* __restrict__ b2,
    const float* __restrict__ b3, const float* __restrict__ b4,
    const float* __restrict__ W5, const float* __restrict__ b5,
    const unsigned short* __restrict__ lstmpk,
    const unsigned short* __restrict__ affpk,
    const unsigned short* __restrict__ decpk,
    float* __restrict__ out) {
  extern __shared__ char smem[];
  float* smf = (float*)smem;
  uint16_t* smh = (uint16_t*)smem;

  const int tid = threadIdx.x;
  const int lane = tid & 63;
  const int wid = tid >> 6;
  const int l15 = lane & 15;
  const int lg = lane >> 4;            // 0..3
  const int rowg = wid & 1;            // row group (32 rows)
  const int colq = wid >> 1;           // col quarter (64 cols per chunk)
  const int r0 = blockIdx.x * 64;
  const int rot = blockIdx.x & 7;      // per-block c-chunk rotation (L2 spread)

  const int arow0 = rowg * 32 + l15;
  const int arow1 = arow0 + 16;
  const uint32_t a_sw = (uint32_t)((l15 & 7) << 4);
  const uint32_t hbase0 = OFF_H + (uint32_t)arow0 * 1024;
  const uint32_t hbase1 = OFF_H + (uint32_t)arow1 * 1024;
  const uint32_t cbase0 = OFF_CODE + (uint32_t)arow0 * 512;
  const uint32_t cbase1 = OFF_CODE + (uint32_t)arow1 * 512;
  const char* lstm_c = (const char*)lstmpk;
  const char* aff_c = (const char*)affpk;
  const char* dec_c = (const char*)decpk;

  // stage one 16KB slab (16 chunks of 1KB; wave w does chunks 2w, 2w+1)
  auto stage_slab = [&](const char* slab_base, int slot) {
    const char* src = slab_base + ((2 * wid) << 10) + (size_t)lane * 16;
    char* dst = smem + OFF_RING + slot * 16384 + ((2 * wid) << 10);
    gload16(src, dst);
    gload16(src + 1024, dst + 1024);
  };

  // ---------------- init LDS ----------------
  // code tile -> bf16, swizzled (row stride 512B)
  {
    int row = tid >> 3;
    int kb0 = (tid & 7) * 8;
    const float* src0 = input + (size_t)(r0 + row) * 259;
#pragma unroll
    for (int it = 0; it < 4; ++it) {
      int kb = kb0 + it * 64;
      const float* src = src0 + kb;
      uint32_t p[4];
#pragma unroll
      for (int jj = 0; jj < 4; ++jj) {
        float f0 = src[2 * jj], f1 = src[2 * jj + 1];
        p[jj] = (uint32_t)f2bf(f0) | ((uint32_t)f2bf(f1) << 16);
      }
      uint32_t byteoff = OFF_CODE + (uint32_t)row * 512 +
                         (uint32_t)((kb * 2) ^ ((row & 7) << 4));
      *(uint4*)(smem + byteoff) = make_uint4(p[0], p[1], p[2], p[3]);
    }
  }
  if (tid < 192) {
    int row = tid / 3, d = tid - row * 3;
    smf[OFF_XYZ / 4 + row * 4 + d] = input[(size_t)(r0 + row) * 259 + 256 + d];
  }
  for (int i = tid; i < 2048; i += 512) {
    int c = i >> 8, jc = i & 255, n = jc >> 4, t15 = jc & 15;
    int grow = (n & 3) * 512 + c * 64 + (n >> 2) * 16 + t15;
    smh[OFF_BIASP / 2 + i] = f2bf(b_ih[grow] + b_hh[grow]);
  }
  if (tid < 256) {
    int u = tid;
    float a0 = v0[u * 3 + 0], a1 = v0[u * 3 + 1], a2 = v0[u * 3 + 2];
    float sc = g0[u] / sqrtf(a0 * a0 + a1 * a1 + a2 * a2);
    smh[OFF_W0N / 2 + u * 3 + 0] = f2bf(a0 * sc);
    smh[OFF_W0N / 2 + u * 3 + 1] = f2bf(a1 * sc);
    smh[OFF_W0N / 2 + u * 3 + 2] = f2bf(a2 * sc);
    smf[OFF_B0 / 4 + u] = b0[u];
    smh[OFF_DB / 2 + 0 * 256 + u] = f2bf(b1[u]);
    smh[OFF_DB / 2 + 1 * 256 + u] = f2bf(b2[u]);
    smh[OFF_DB / 2 + 2 * 256 + u] = f2bf(b3[u]);
    smh[OFF_DB / 2 + 3 * 256 + u] = f2bf(b4[u]);
    smf[OFF_W5 / 4 + u] = W5[u];
  }
  if (tid < 6) smf[OFF_MISC / 4 + tid] = b_aff[tid];
  if (tid == 6) smf[OFF_MISC / 4 + 6] = b5[0];
  __syncthreads();

  // prologue for step-0 stream: slabs (rot*25 + {0,1}) -> slots 0,1
  stage_slab(lstm_c + ((size_t)(rot * 25) << 14), 0);
  stage_slab(lstm_c + ((size_t)(rot * 25 + 1) << 14), 1);

  // persistent cell state + staged h
  float creg[8][8];
#pragma unroll
  for (int c = 0; c < 8; ++c)
#pragma unroll
    for (int e = 0; e < 8; ++e) creg[c][e] = 0.f;
  uint32_t hst[8][4];

  // ======================= 8 LSTM steps =======================
  for (int step = 0; step < 8; ++step) {
    const int per_c = step ? 25 : 9;       // step 0: h==0, skip h-tiles
    const int count = per_c * 8 + 1;       // + W_aff slab at stream end

    // xyz A-fragment (k-tile tb==8: real k = 0..2, lg==0 lanes only)
    v8s xyzA0 = {0, 0, 0, 0, 0, 0, 0, 0}, xyzA1 = {0, 0, 0, 0, 0, 0, 0, 0};
    if (lg == 0) {
      xyzA0[0] = (short)f2bf(smf[OFF_XYZ / 4 + arow0 * 4 + 0]);
      xyzA0[1] = (short)f2bf(smf[OFF_XYZ / 4 + arow0 * 4 + 1]);
      xyzA0[2] = (short)f2bf(smf[OFF_XYZ / 4 + arow0 * 4 + 2]);
      xyzA1[0] = (short)f2bf(smf[OFF_XYZ / 4 + arow1 * 4 + 0]);
      xyzA1[1] = (short)f2bf(smf[OFF_XYZ / 4 + arow1 * 4 + 1]);
      xyzA1[2] = (short)f2bf(smf[OFF_XYZ / 4 + arow1 * 4 + 2]);
    }

    // stream state: prologue (slots 0,1) staged in previous tail / init
    int sS = 2, stbs = 2, scs_phys = rot, rs = 2, sb = 0;

    v4f acc0[4], acc1[4];
    auto phz = [&](v8s af0, v8s af1) {
      asm volatile("s_waitcnt vmcnt(2)" ::: "memory");
      __builtin_amdgcn_s_barrier();
      if (sS < count) {
        const char* src;
        if (sS == count - 1) {
          src = aff_c + ((2 * wid) << 10) + (size_t)lane * 16;
        } else {
          src = lstm_c + (((size_t)((scs_phys * 25 + stbs) * 16 + 2 * wid)) << 10)
              + (size_t)lane * 16;
          if (++stbs == per_c) { stbs = 0; scs_phys = (scs_phys + 1) & 7; }
        }
        char* dst = smem + OFF_RING + rs * 16384 + ((2 * wid) << 10);
        gload16(src, dst);
        gload16(src + 1024, dst + 1024);
        ++sS;
        rs = (rs == 2) ? 0 : rs + 1;
      }
      const char* sl = smem + OFF_RING + sb * 16384 + (colq << 12) + (lane << 4);
      __builtin_amdgcn_s_setprio(1);
#pragma unroll
      for (int fi = 0; fi < 4; ++fi) {
        v8s bf = *(const v8s*)(sl + (fi << 10));
        acc0[fi] = MFMA16(af0, bf, acc0[fi]);
        acc1[fi] = MFMA16(af1, bf, acc1[fi]);
      }
      __builtin_amdgcn_s_setprio(0);
      sb = (sb == 2) ? 0 : sb + 1;
    };

#pragma unroll
    for (int ci = 0; ci < 8; ++ci) {
      const int cphys = (ci + rot) & 7;
      // acc init: bias (bf16-exact) for columns of chunk cphys
#pragma unroll
      for (int fi = 0; fi < 4; ++fi) {
        float bb = bf2f(smh[OFF_BIASP / 2 + cphys * 256 + (colq * 4 + fi) * 16 + l15]);
        acc0[fi][0] = bb; acc0[fi][1] = bb; acc0[fi][2] = bb; acc0[fi][3] = bb;
        acc1[fi][0] = bb; acc1[fi][1] = bb; acc1[fi][2] = bb; acc1[fi][3] = bb;
      }
      // code k-tiles (A from LDS code tile)
#pragma unroll 2
      for (int t = 0; t < 8; ++t) {
        uint32_t ko = (uint32_t)(t * 64 + lg * 16);
        v8s af0 = *(const v8s*)(smem + cbase0 + (ko ^ a_sw));
        v8s af1 = *(const v8s*)(smem + cbase1 + (ko ^ a_sw));
        phz(af0, af1);
      }
      // xyz k-tile
      phz(xyzA0, xyzA1);
      // h k-tiles (steps >= 1)
      if (step > 0) {
#pragma unroll 2
        for (int t2 = 0; t2 < 16; ++t2) {
          uint32_t ko = (uint32_t)(t2 * 64 + lg * 16);
          v8s af0 = *(const v8s*)(smem + hbase0 + (ko ^ a_sw));
          v8s af1 = *(const v8s*)(smem + hbase1 + (ko ^ a_sw));
          phz(af0, af1);
        }
      }
      // lane-local cell update
#define CELLUP(AQ, M) do {                                                   \
        uint32_t plo = 0, phi = 0;                                           \
        _Pragma("unroll")                                                    \
        for (int j = 0; j < 4; ++j) {                                        \
          float gi = AQ[0][j], gf = AQ[1][j], gg = AQ[2][j], go = AQ[3][j];  \
          float cc = creg[ci][(M) * 4 + j];                                  \
          cc = sigf(gf) * cc + sigf(gi) * tanh_fast(gg);                     \
          creg[ci][(M) * 4 + j] = cc;                                        \
          uint32_t hb = f2bf(sigf(go) * tanh_fast(cc));                      \
          if (j < 2) plo |= hb << (16 * j); else phi |= hb << (16 * (j - 2));\
        }                                                                    \
        hst[ci][(M) * 2 + 0] = plo; hst[ci][(M) * 2 + 1] = phi; } while (0)
      CELLUP(acc0, 0);
      CELLUP(acc1, 1);
#undef CELLUP
    }

    // drain the W_aff slab (and everything else) BEFORE the barrier so the
    // post-barrier aff read sees all waves' chunks landed.
    asm volatile("s_waitcnt vmcnt(0)" ::: "memory");
    __syncthreads();  // all h_old reads complete
    // write new h (bf16, swizzled); columns follow the rotated chunk order
#pragma unroll
    for (int ci = 0; ci < 8; ++ci) {
      const int cphys = (ci + rot) & 7;
#pragma unroll
      for (int m = 0; m < 2; ++m)
#pragma unroll
        for (int j = 0; j < 4; ++j) {
          int u = cphys * 64 + colq * 16 + l15;
          int rr = rowg * 32 + m * 16 + lg * 4 + j;
          uint32_t val = ((j < 2) ? (hst[ci][m * 2] >> (16 * j))
                                  : (hst[ci][m * 2 + 1] >> (16 * (j - 2)))) & 0xffffu;
          *(unsigned short*)(smem + OFF_H + (uint32_t)rr * 1024 +
                             (uint32_t)((u * 2) ^ ((rr & 7) << 4))) = (unsigned short)val;
        }
    }
    __syncthreads();
    // a = h @ W_aff^T + b_aff  (waves 0,1; B slab = last ring slot of stream)
    {
      const uint32_t affslot = (uint32_t)(((count - 1) % 3) * 16384);
      if (wid < 2) {
        v4f a0 = {0.f, 0.f, 0.f, 0.f}, a1v = {0.f, 0.f, 0.f, 0.f};
#pragma unroll 2
        for (int t = 0; t < 16; ++t) {
          uint32_t ko = (uint32_t)(t * 64 + lg * 16);
          v8s bf = *(const v8s*)(smem + OFF_RING + affslot + (t << 10) + (lane << 4));
          v8s af0 = *(const v8s*)(smem + hbase0 + (ko ^ a_sw));
          v8s af1 = *(const v8s*)(smem + hbase1 + (ko ^ a_sw));
          a0 = MFMA16(af0, bf, a0);
          a1v = MFMA16(af1, bf, a1v);
        }
        if (l15 < 6) {
          float ba = smf[OFF_MISC / 4 + l15];
#pragma unroll
          for (int j = 0; j < 4; ++j) {
            smf[OFF_A / 4 + (rowg * 32 + lg * 4 + j) * 8 + l15] = a0[j] + ba;
            smf[OFF_A / 4 + (rowg * 32 + 16 + lg * 4 + j) * 8 + l15] = a1v[j] + ba;
          }
        }
      }
    }
    __syncthreads();  // aff reads of ring complete; OFF_A published
    // stage next stream's prologue (slots 0,1): next step's slabs, or decoder
    {
      const char* nsrc = (step == 7) ? dec_c : (lstm_c + ((size_t)(rot * 25) << 14));
      stage_slab(nsrc, 0);
      stage_slab(nsrc + 16384, 1);
    }
    // xyz = a[3:] + (1 + a[:3]) * xyz
    if (tid < 192) {
      int rr = tid / 3, d = tid - rr * 3;
      float ad = smf[OFF_A / 4 + rr * 8 + d];
      float a3 = smf[OFF_A / 4 + rr * 8 + 3 + d];
      float old = smf[OFF_XYZ / 4 + rr * 4 + d];
      smf[OFF_XYZ / 4 + rr * 4 + d] = a3 + (1.f + ad) * old;
    }
    __syncthreads();
  }

  // ======================= decoder =======================
  // decoder prologue (slabs 0,1) already staged in step-7 tail.
  // layer 0: 3 -> 256 (VALU), write xA at OFF_H
  {
    int row = tid & 63;
    int ublk = tid >> 6;
    float p0 = smf[OFF_XYZ / 4 + row * 4 + 0];
    float p1 = smf[OFF_XYZ / 4 + row * 4 + 1];
    float p2 = smf[OFF_XYZ / 4 + row * 4 + 2];
#pragma unroll
    for (int gq = 0; gq < 4; ++gq) {
      int u0 = ublk * 32 + gq * 8;
      uint32_t pk[4];
#pragma unroll
      for (int jj = 0; jj < 8; ++jj) {
        int uu = u0 + jj;
        float val = smf[OFF_B0 / 4 + uu]
                  + bf2f(smh[OFF_W0N / 2 + uu * 3 + 0]) * p0
                  + bf2f(smh[OFF_W0N / 2 + uu * 3 + 1]) * p1
                  + bf2f(smh[OFF_W0N / 2 + uu * 3 + 2]) * p2;
        val = fmaxf(val, 0.f);
        ((unsigned short*)pk)[jj] = f2bf(val);
      }
      *(uint4*)(smem + OFF_H + (uint32_t)row * 512 +
                (uint32_t)((u0 * 2) ^ ((row & 7) << 4))) = *(uint4*)pk;
    }
  }
  __syncthreads();

  // layers 1..4: 256 -> 256 MFMA, staged B (ring 3), ping-pong x tiles
  {
    int ps = 2, rs = 2, sb = 0;
#pragma unroll
    for (int L = 0; L < 4; ++L) {
      v4f acc0[4], acc1[4];
#pragma unroll
      for (int fi = 0; fi < 4; ++fi) {
        float bb = bf2f(smh[OFF_DB / 2 + L * 256 + (colq * 4 + fi) * 16 + l15]);
        acc0[fi][0] = bb; acc0[fi][1] = bb; acc0[fi][2] = bb; acc0[fi][3] = bb;
        acc1[fi][0] = bb; acc1[fi][1] = bb; acc1[fi][2] = bb; acc1[fi][3] = bb;
      }
      uint32_t xin = OFF_H + (uint32_t)((L & 1) * 32768);
      uint32_t ab0 = xin + (uint32_t)arow0 * 512;
      uint32_t ab1 = xin + (uint32_t)arow1 * 512;
#pragma unroll
      for (int t = 0; t < 8; ++t) {
        uint32_t ko = (uint32_t)(t * 64 + lg * 16);
        v8s af0 = *(const v8s*)(smem + ab0 + (ko ^ a_sw));
        v8s af1 = *(const v8s*)(smem + ab1 + (ko ^ a_sw));
        if (L == 3 && t == 7) { asm volatile("s_waitcnt vmcnt(0)" ::: "memory"); }
        else                  { asm volatile("s_waitcnt vmcnt(2)" ::: "memory"); }
        __builtin_amdgcn_s_barrier();
        if (ps < 32) {
          const char* src = dec_c + (((size_t)(ps * 16 + 2 * wid)) << 10) + (size_t)lane * 16;
          char* dst = smem + OFF_RING + rs * 16384 + ((2 * wid) << 10);
          gload16(src, dst);
          gload16(src + 1024, dst + 1024);
          ps++;
          rs = (rs == 2) ? 0 : rs + 1;
        }
        const char* sl = smem + OFF_RING + sb * 16384 + (colq << 12) + (lane << 4);
        __builtin_amdgcn_s_setprio(1);
#pragma unroll
        for (int fi = 0; fi < 4; ++fi) {
          v8s bf = *(const v8s*)(sl + (fi << 10));
          acc0[fi] = MFMA16(af0, bf, acc0[fi]);
          acc1[fi] = MFMA16(af1, bf, acc1[fi]);
        }
        __builtin_amdgcn_s_setprio(0);
        sb = (sb == 2) ? 0 : sb + 1;
      }
      uint32_t xout = OFF_H + (uint32_t)(((L + 1) & 1) * 32768);
#pragma unroll
      for (int fi = 0; fi < 4; ++fi) {
        int coli = (colq * 4 + fi) * 16 + l15;
#pragma unroll
        for (int j = 0; j < 4; ++j) {
          int rr0 = rowg * 32 + lg * 4 + j;
          int rr1 = rr0 + 16;
          *(unsigned short*)(smem + xout + (uint32_t)rr0 * 512 +
                             (uint32_t)((coli * 2) ^ ((rr0 & 7) << 4))) = f2bf(fmaxf(acc0[fi][j], 0.f));
          *(unsigned short*)(smem + xout + (uint32_t)rr1 * 512 +
                             (uint32_t)((coli * 2) ^ ((rr1 & 7) << 4))) = f2bf(fmaxf(acc1[fi][j], 0.f));
        }
      }
      __syncthreads();
    }
  }

  // layer 5: 256 -> 1 (wave dot + butterfly reduce); final x at OFF_H
  {
    float b5v = smf[OFF_MISC / 4 + 6];
    for (int rr = 0; rr < 8; ++rr) {
      int r = wid * 8 + rr;
      uint32_t byteoff = OFF_H + (uint32_t)r * 512 + (uint32_t)((lane * 8) ^ ((r & 7) << 4));
      uint2 xv = *(const uint2*)(smem + byteoff);
      float p = 0.f;
#pragma unroll
      for (int jj = 0; jj < 4; ++jj) {
        unsigned short us = (unsigned short)(((jj < 2) ? (xv.x >> (16 * jj))
                                                       : (xv.y >> (16 * (jj - 2)))) & 0xffffu);
        p += bf2f(us) * smf[OFF_W5 / 4 + lane * 4 + jj];
      }
#pragma unroll
      for (int off = 32; off >= 1; off >>= 1) p += __shfl_xor(p, off, 64);
      if (lane == 0) out[r0 + r] = p + b5v;
    }
  }
}

// ============================================================================
extern "C" void kernel_launch(void* const* d_in, const int* in_sizes, int n_in,
                              void* d_out, int out_size, void* d_ws, size_t ws_size,
                              hipStream_t stream) {
  const float* input = (const float*)d_in[0];
  const float* W_ih  = (const float*)d_in[1];
  const float* b_ih  = (const float*)d_in[2];
  const float* W_hh  = (const float*)d_in[3];
  const float* b_hh  = (const float*)d_in[4];
  const float* W_aff = (const float*)d_in[5];
  const float* b_aff = (const float*)d_in[6];
  const float* v0 = (const float*)d_in[7];
  const float* g0 = (const float*)d_in[8];
  const float* b0 = (const float*)d_in[9];
  const float* v1 = (const float*)d_in[10];
  const float* g1 = (const float*)d_in[11];
  const float* b1 = (const float*)d_in[12];
  const float* v2 = (const float*)d_in[13];
  const float* g2 = (const float*)d_in[14];
  const float* b2 = (const float*)d_in[15];
  const float* v3 = (const float*)d_in[16];
  const float* g3 = (const float*)d_in[17];
  const float* b3 = (const float*)d_in[18];
  const float* v4 = (const float*)d_in[19];
  const float* g4 = (const float*)d_in[20];
  const float* b4 = (const float*)d_in[21];
  const float* W5 = (const float*)d_in[22];
  const float* b5 = (const float*)d_in[23];

  char* ws = (char*)d_ws;
  unsigned short* lstmpk = (unsigned short*)(ws + WS_LSTMPK);
  unsigned short* affpk  = (unsigned short*)(ws + WS_AFFPK);
  unsigned short* decpk  = (unsigned short*)(ws + WS_DECPK);
  float* dscale = (float*)(ws + WS_DSCALE);
  float* outp = (float*)d_out;

  (void)in_sizes; (void)n_in; (void)out_size; (void)ws_size;

  hipFuncSetAttribute((const void*)lstm_main,
                      hipFuncAttributeMaxDynamicSharedMemorySize, SMEM_BYTES);

  dec_norm_kernel<<<4, 256, 0, stream>>>(v1, v2, v3, v4, g1, g2, g3, g4, dscale);
  pack_kernel<<<7456, 256, 0, stream>>>(W_ih, W_hh, W_aff, v1, v2, v3, v4, dscale,
                                        lstmpk, affpk, decpk);
  lstm_main<<<1024, 512, SMEM_BYTES, stream>>>(
      input, b_ih, b_hh, b_aff, v0, g0, b0, b1, b2, b3, b4, W5, b5,
      lstmpk, affpk, decpk, outp);
}